// Round 14
// baseline (633.346 us; speedup 1.0000x reference)
//
#include <hip/hip_runtime.h>
#include <hip/hip_bf16.h>

// Problem constants (fixed by setup_inputs)
#define NN 8192
#define FF 512
#define HH 256
#define RR 16
#define BB 32
#define LL 256
#define CC 7
#define EE 262144
#define NBASE 30
#define DD 768

constexpr int FLAG_BIAS = 1, FLAG_RELU = 4,
              FLAG_SPLITOUT = 16, FLAG_TAILOUT = 32, FLAG_TAIL2 = 64;

typedef __attribute__((ext_vector_type(8))) short bf16x8;
typedef __attribute__((ext_vector_type(4))) float f32x4;

// ------------- dtype detection (robustness) -----------------------------------
__global__ __launch_bounds__(256) void detect_dtype(const unsigned short* __restrict__ xs,
                                                    int* __restrict__ flag) {
  __shared__ int red[256];
  int cnt = 0;
  for (int i = threadIdx.x * 2; i < 8192; i += 512) {
    unsigned short u = xs[i];
    int e = (u >> 7) & 0xFF;
    if (e >= 0xC0) cnt++;
  }
  red[threadIdx.x] = cnt;
  __syncthreads();
  for (int s = 128; s > 0; s >>= 1) {
    if (threadIdx.x < s) red[threadIdx.x] += red[threadIdx.x + s];
    __syncthreads();
  }
  if (threadIdx.x == 0) flag[0] = (red[0] > 16) ? 1 : 0;  // 1 = fp32 data
}

// ------------- unified prep: conversions + transposed splits, one launch -------
struct PSeg {
  const void* src;
  float* dst;
  __hip_bfloat16* hi;
  __hip_bfloat16* lo;
  long n;
  int R, C, ld, off;     // transpose geometry (type==1)
  int type;              // 0 = linear, 1 = transpose-split
  int zero;
};
struct PTable {
  PSeg seg[18];
  int count;
  long total;
};

__global__ __launch_bounds__(256) void prep_all(PTable t, const int* __restrict__ flag) {
  const int fp32 = flag[0];
  for (long i = (long)blockIdx.x * 256 + threadIdx.x; i < t.total;
       i += (long)gridDim.x * 256) {
    long off = i;
    int s = 0;
    while (off >= t.seg[s].n) { off -= t.seg[s].n; s++; }
    const PSeg& sg = t.seg[s];
    if (sg.type == 0) {
      float v = 0.f;
      if (!sg.zero)
        v = fp32 ? ((const float*)sg.src)[off]
                 : __bfloat162float(((const __hip_bfloat16*)sg.src)[off]);
      if (sg.dst) sg.dst[off] = v;
      if (sg.hi) {
        __hip_bfloat16 h = __float2bfloat16(v);
        sg.hi[off] = h;
        sg.lo[off] = __float2bfloat16(v - __bfloat162float(h));
      }
    } else {
      int r = (int)(off % sg.R), c = (int)(off / sg.R);
      float v = fp32 ? ((const float*)sg.src)[(long)r * sg.C + c]
                     : __bfloat162float(((const __hip_bfloat16*)sg.src)[(long)r * sg.C + c]);
      __hip_bfloat16 h = __float2bfloat16(v);
      long d = (long)c * sg.ld + sg.off + r;
      sg.hi[d] = h;
      sg.lo[d] = __float2bfloat16(v - __bfloat162float(h));
    }
  }
}

// copy x_hi/x_lo [8192][512] into em_hi/lo [8192][768] cols 0:512
__global__ __launch_bounds__(256) void copy_xsplit_k(
    const __hip_bfloat16* __restrict__ xh, const __hip_bfloat16* __restrict__ xl,
    __hip_bfloat16* __restrict__ eh, __hip_bfloat16* __restrict__ el) {
  int idx = blockIdx.x * 256 + threadIdx.x;  // 8192*512
  int n = idx >> 9, f = idx & 511;
  long d = (long)n * DD + f;
  eh[d] = xh[idx];
  el[d] = xl[idx];
}

// ---- wt_nat[r][f][h] = sum_b comp[r,b]*basis[b][f][h] ------------------------
__global__ __launch_bounds__(256) void wt_gemm(
    const float* __restrict__ basis, const float* __restrict__ comp,
    float* __restrict__ wt_nat) {
  __shared__ float cs[RR * NBASE];
  int tid = threadIdx.x;
  for (int i = tid; i < RR * NBASE; i += 256) cs[i] = comp[i];
  __syncthreads();
  long col = (long)blockIdx.x * 256 + tid;
  float acc[RR] = {};
  for (int b = 0; b < NBASE; ++b) {
    float v = basis[(long)b * 131072 + col];
#pragma unroll
    for (int r = 0; r < RR; ++r) acc[r] += cs[r * NBASE + b] * v;
  }
#pragma unroll
  for (int r = 0; r < RR; ++r) wt_nat[(long)r * 131072 + col] = acc[r];
}

// ---- wt_nat [16][512][256] (r,f,h) -> wtc[(r*256+h)][512] hi/lo --------------
__global__ __launch_bounds__(256) void wt_transpose(
    const float* __restrict__ wt_nat,
    __hip_bfloat16* __restrict__ hi, __hip_bfloat16* __restrict__ lo) {
  __shared__ float t[32][33];
  const int r = blockIdx.z;
  const int f0 = blockIdx.y * 32, h0 = blockIdx.x * 32;
  const int c = threadIdx.x & 31, rw = threadIdx.x >> 5;
  const float* src = wt_nat + ((long)r * 512 + f0) * 256 + h0;
#pragma unroll
  for (int i = 0; i < 4; ++i)
    t[rw + i * 8][c] = src[(long)(rw + i * 8) * 256 + c];
  __syncthreads();
#pragma unroll
  for (int i = 0; i < 4; ++i) {
    int hh = rw + i * 8;
    float v = t[c][hh];
    long orow = (long)(r * 256 + h0 + hh) * 512 + f0 + c;
    __hip_bfloat16 hv = __float2bfloat16(v);
    hi[orow] = hv;
    lo[orow] = __float2bfloat16(v - __bfloat162float(hv));
  }
}

// ---------------- fused dual-precision MFMA GEMM ------------------------------
__device__ __forceinline__ void gload_lds16(const void* g, void* l) {
  __builtin_amdgcn_global_load_lds(
      (const __attribute__((address_space(1))) unsigned int*)g,
      (__attribute__((address_space(3))) unsigned int*)l, 16, 0, 0);
}

__global__ __launch_bounds__(256, 3) void mfma_dual(
    const __hip_bfloat16* __restrict__ A, const __hip_bfloat16* __restrict__ Alo,
    const __hip_bfloat16* __restrict__ Bt, const __hip_bfloat16* __restrict__ Btlo,
    const float* __restrict__ bias, float* __restrict__ C, float* __restrict__ Ct,
    __hip_bfloat16* __restrict__ Chi, __hip_bfloat16* __restrict__ Clo,
    __hip_bfloat16* __restrict__ Chi2, __hip_bfloat16* __restrict__ Clo2,
    int K, int ldc, long sA, long sB, long sC, int flags) {
  __shared__ __hip_bfloat16 Ah[128 * 32];
  __shared__ __hip_bfloat16 Bh[128 * 32];
  __shared__ __hip_bfloat16 Al[128 * 32];
  __shared__ __hip_bfloat16 Bl[128 * 32];
  const int tid = threadIdx.x;
  const int w = tid >> 6, lane = tid & 63;
  const long z = blockIdx.z;
  const long row0 = (long)blockIdx.y * 128, col0 = (long)blockIdx.x * 128;
  const int wm = w & 1, wn = w >> 1;
  const int srow0 = (w * 128 + lane) >> 2;
  const int srow1 = (w * 128 + 64 + lane) >> 2;
  const int kch = (lane & 3) * 8;
  const int fr = lane & 15, q = lane >> 4;
  const bool hasAlo = (Alo != nullptr);
  const __hip_bfloat16* Az = A + z * sA;
  const __hip_bfloat16* Alz = hasAlo ? (Alo + z * sA) : nullptr;
  const __hip_bfloat16* Bz = Bt + z * sB;
  const __hip_bfloat16* Blz = Btlo + z * sB;
  const long aoff0 = (row0 + srow0) * K + kch, aoff1 = (row0 + srow1) * K + kch;
  const long boff0 = (col0 + srow0) * K + kch, boff1 = (col0 + srow1) * K + kch;
  f32x4 acc[4][4] = {};
  for (int k0 = 0; k0 < K; k0 += 32) {
    gload_lds16(Az + aoff0 + k0, Ah + w * 1024);
    gload_lds16(Az + aoff1 + k0, Ah + w * 1024 + 512);
    gload_lds16(Bz + boff0 + k0, Bh + w * 1024);
    gload_lds16(Bz + boff1 + k0, Bh + w * 1024 + 512);
    gload_lds16(Blz + boff0 + k0, Bl + w * 1024);
    gload_lds16(Blz + boff1 + k0, Bl + w * 1024 + 512);
    if (hasAlo) {
      gload_lds16(Alz + aoff0 + k0, Al + w * 1024);
      gload_lds16(Alz + aoff1 + k0, Al + w * 1024 + 512);
    }
    __syncthreads();
    bf16x8 ah[4], bh[4], bl[4];
#pragma unroll
    for (int i = 0; i < 4; ++i) {
      ah[i] = *(const bf16x8*)&Ah[(wm * 64 + i * 16 + fr) * 32 + q * 8];
      bh[i] = *(const bf16x8*)&Bh[(wn * 64 + i * 16 + fr) * 32 + q * 8];
      bl[i] = *(const bf16x8*)&Bl[(wn * 64 + i * 16 + fr) * 32 + q * 8];
    }
#pragma unroll
    for (int i = 0; i < 4; ++i)
#pragma unroll
      for (int j = 0; j < 4; ++j) {
        acc[i][j] = __builtin_amdgcn_mfma_f32_16x16x32_bf16(ah[i], bh[j], acc[i][j], 0, 0, 0);
        acc[i][j] = __builtin_amdgcn_mfma_f32_16x16x32_bf16(ah[i], bl[j], acc[i][j], 0, 0, 0);
      }
    if (hasAlo) {
      bf16x8 al[4];
#pragma unroll
      for (int i = 0; i < 4; ++i)
        al[i] = *(const bf16x8*)&Al[(wm * 64 + i * 16 + fr) * 32 + q * 8];
#pragma unroll
      for (int i = 0; i < 4; ++i)
#pragma unroll
        for (int j = 0; j < 4; ++j)
          acc[i][j] = __builtin_amdgcn_mfma_f32_16x16x32_bf16(al[i], bh[j], acc[i][j], 0, 0, 0);
    }
    __syncthreads();
  }
  const int cr = (lane >> 4) * 4, cc = lane & 15;
  float* Cz = C ? (C + z * sC) : nullptr;
  __hip_bfloat16* Chz = Chi ? (Chi + z * sC) : nullptr;
  __hip_bfloat16* Clz = Clo ? (Clo + z * sC) : nullptr;
#pragma unroll
  for (int i = 0; i < 4; ++i) {
    long rbase = row0 + wm * 64 + i * 16 + cr;
#pragma unroll
    for (int j = 0; j < 4; ++j) {
      long col = col0 + wn * 64 + j * 16 + cc;
      float bv = (flags & FLAG_BIAS) ? bias[col] : 0.f;
#pragma unroll
      for (int r = 0; r < 4; ++r) {
        float v = acc[i][j][r] + bv;
        if (flags & FLAG_RELU) v = fmaxf(v, 0.f);
        long row = rbase + r;
        if ((flags & FLAG_TAIL2) && col >= 768) {
          long off2 = (row >> 8) * 65536 + (col - 768) * 256 + (row & 255);
          __hip_bfloat16 hv = __float2bfloat16(v);
          Chi2[off2] = hv;
          Clo2[off2] = __float2bfloat16(v - __bfloat162float(hv));
        } else if (flags & FLAG_SPLITOUT) {
          long off = row * ldc + col;
          __hip_bfloat16 hv = __float2bfloat16(v);
          Chz[off] = hv;
          Clz[off] = __float2bfloat16(v - __bfloat162float(hv));
        } else if ((flags & FLAG_TAILOUT) && col >= 4096) {
          Ct[row * 256 + (col - 4096)] = v;
        } else {
          Cz[row * ldc + col] = v;
        }
      }
    }
  }
}

// ---------------- fused scores GEMM + tanh + softmax --------------------------
// Block = 128 t-rows x all 256 s-cols of batch z; grid (1, 2, 32).
// a[t][s] = exp(tanh(X_t . em_s)) / sum_s  (|tanh|<=1 so no max-subtract needed)
__global__ __launch_bounds__(256) void score_softmax(
    const __hip_bfloat16* __restrict__ Xh, const __hip_bfloat16* __restrict__ Xl,
    const __hip_bfloat16* __restrict__ Eh, const __hip_bfloat16* __restrict__ El,
    __hip_bfloat16* __restrict__ Ab) {
  __shared__ __hip_bfloat16 AhS[128 * 32];
  __shared__ __hip_bfloat16 AlS[128 * 32];
  __shared__ __hip_bfloat16 BhS[256 * 32];
  __shared__ __hip_bfloat16 BlS[256 * 32];
  __shared__ float rsum[128][2];
  const int tid = threadIdx.x;
  const int w = tid >> 6, lane = tid & 63;
  const long z = blockIdx.z;
  const long row0 = (long)blockIdx.y * 128;
  const int wm = w & 1, wn = w >> 1;           // wave: 64 rows x 128 cols
  const int kch = (lane & 3) * 8;
  const int fr = lane & 15, q = lane >> 4;
  const __hip_bfloat16* Axh = Xh + z * (LL * DD);
  const __hip_bfloat16* Axl = Xl + z * (LL * DD);
  const __hip_bfloat16* Beh = Eh + z * (LL * DD);
  const __hip_bfloat16* Bel = El + z * (LL * DD);
  const int sa0 = w * 32 + (lane >> 2), sa1 = sa0 + 16;           // A rows staged
  const int sb0 = w * 64 + (lane >> 2);                           // B rows staged
  f32x4 acc[4][8] = {};
  for (int k0 = 0; k0 < DD; k0 += 32) {
    gload_lds16(Axh + (row0 + sa0) * DD + kch + k0, AhS + w * 1024);
    gload_lds16(Axh + (row0 + sa1) * DD + kch + k0, AhS + w * 1024 + 512);
    gload_lds16(Axl + (row0 + sa0) * DD + kch + k0, AlS + w * 1024);
    gload_lds16(Axl + (row0 + sa1) * DD + kch + k0, AlS + w * 1024 + 512);
#pragma unroll
    for (int b = 0; b < 4; ++b) {
      gload_lds16(Beh + (sb0 + b * 16) * DD + kch + k0, BhS + w * 2048 + b * 512);
      gload_lds16(Bel + (sb0 + b * 16) * DD + kch + k0, BlS + w * 2048 + b * 512);
    }
    __syncthreads();
    bf16x8 ah[4], al[4];
#pragma unroll
    for (int i = 0; i < 4; ++i) {
      ah[i] = *(const bf16x8*)&AhS[(wm * 64 + i * 16 + fr) * 32 + q * 8];
      al[i] = *(const bf16x8*)&AlS[(wm * 64 + i * 16 + fr) * 32 + q * 8];
    }
#pragma unroll
    for (int j = 0; j < 8; ++j) {
      bf16x8 bh = *(const bf16x8*)&BhS[(wn * 128 + j * 16 + fr) * 32 + q * 8];
      bf16x8 bl = *(const bf16x8*)&BlS[(wn * 128 + j * 16 + fr) * 32 + q * 8];
#pragma unroll
      for (int i = 0; i < 4; ++i) {
        acc[i][j] = __builtin_amdgcn_mfma_f32_16x16x32_bf16(ah[i], bh, acc[i][j], 0, 0, 0);
        acc[i][j] = __builtin_amdgcn_mfma_f32_16x16x32_bf16(ah[i], bl, acc[i][j], 0, 0, 0);
        acc[i][j] = __builtin_amdgcn_mfma_f32_16x16x32_bf16(al[i], bh, acc[i][j], 0, 0, 0);
      }
    }
    __syncthreads();
  }
  const int cc = lane & 15;
  // exp(tanh(.)) in place, then row-sum: over j (regs) then over cc (shuffle)
#pragma unroll
  for (int i = 0; i < 4; ++i) {
#pragma unroll
    for (int rr = 0; rr < 4; ++rr) {
      float s = 0.f;
#pragma unroll
      for (int j = 0; j < 8; ++j) {
        float e = __expf(tanhf(acc[i][j][rr]));
        acc[i][j][rr] = e;
        s += e;
      }
      s += __shfl_xor(s, 1);
      s += __shfl_xor(s, 2);
      s += __shfl_xor(s, 4);
      s += __shfl_xor(s, 8);
      if (cc == 0) rsum[wm * 64 + i * 16 + q * 4 + rr][wn] = s;
    }
  }
  __syncthreads();
  __hip_bfloat16* Az = Ab + z * 65536;
#pragma unroll
  for (int i = 0; i < 4; ++i) {
#pragma unroll
    for (int rr = 0; rr < 4; ++rr) {
      int rloc = wm * 64 + i * 16 + q * 4 + rr;
      float S = rsum[rloc][0] + rsum[rloc][1];
      float invS = 1.0f / S;
      long rb = (row0 + rloc) * 256;
#pragma unroll
      for (int j = 0; j < 8; ++j)
        Az[rb + wn * 128 + j * 16 + cc] = __float2bfloat16(acc[i][j][rr] * invS);
    }
  }
}

// ---------------- edge kernels: CSR build + gathers ----------------------------
__global__ __launch_bounds__(256) void count_edges(
    const int* __restrict__ ei, const int* __restrict__ et, float* __restrict__ cnt) {
  int e = blockIdx.x * 256 + threadIdx.x;
  if (e < EE) atomicAdd(&cnt[ei[EE + e] * RR + et[e]], 1.0f);
}

__global__ __launch_bounds__(256) void scan_rowptr(
    const float* __restrict__ cntf, int* __restrict__ rowptr, int* __restrict__ fill) {
  __shared__ int part[256];
  int tid = threadIdx.x;
  int base = tid * 32;
  int local[32];
  int s = 0;
  for (int i = 0; i < 32; ++i) {
    local[i] = s;
    const float* c = &cntf[(base + i) * RR];
    int d = 0;
#pragma unroll
    for (int r = 0; r < RR; ++r) d += (int)c[r];
    s += d;
  }
  part[tid] = s;
  __syncthreads();
  for (int off = 1; off < 256; off <<= 1) {
    int v = (tid >= off) ? part[tid - off] : 0;
    __syncthreads();
    part[tid] += v;
    __syncthreads();
  }
  int prev = (tid == 0) ? 0 : part[tid - 1];
  for (int i = 0; i < 32; ++i) rowptr[base + i] = prev + local[i];
  if (tid == 255) rowptr[8192] = part[255];
  for (int i = tid; i < 8192; i += 256) fill[i] = 0;
}

__global__ __launch_bounds__(256) void edge_fill(
    const int* __restrict__ ei, const int* __restrict__ et,
    const int* __restrict__ rowptr, int* __restrict__ fill, int* __restrict__ eidx) {
  int e = blockIdx.x * 256 + threadIdx.x;
  if (e < EE) {
    int dst = ei[EE + e];
    int pos = rowptr[dst] + atomicAdd(&fill[dst], 1);
    eidx[pos] = ei[e] | (et[e] << 16);
  }
}

// out1 += mean-agg; also emit split into a2o1 cols 256:512 (A of out2 GEMM)
__global__ __launch_bounds__(256) void rgcn_gather(
    const int* __restrict__ rowptr, const int* __restrict__ eidx,
    const float* __restrict__ cntf, const float* __restrict__ xw,
    float* __restrict__ out1, __hip_bfloat16* __restrict__ a2o1_hi,
    __hip_bfloat16* __restrict__ a2o1_lo) {
  const int dst = blockIdx.x;
  const int h = threadIdx.x;
  __shared__ float inv[RR];
  __shared__ int se[256];
  if (h < RR) inv[h] = 1.0f / fmaxf(cntf[dst * RR + h], 1.0f);
  const int beg = rowptr[dst], end = rowptr[dst + 1];
  float a0 = 0.f, a1 = 0.f, a2 = 0.f, a3 = 0.f;
  for (int c0 = beg; c0 < end; c0 += 256) {
    int n = min(256, end - c0);
    __syncthreads();
    if (h < n) se[h] = eidx[c0 + h];
    __syncthreads();
    int i = 0;
    for (; i + 4 <= n; i += 4) {
      int p0 = se[i], p1 = se[i + 1], p2 = se[i + 2], p3 = se[i + 3];
      float v0 = xw[((long)(p0 & 0xFFFF) << 12) + ((p0 >> 16) << 8) + h];
      float v1 = xw[((long)(p1 & 0xFFFF) << 12) + ((p1 >> 16) << 8) + h];
      float v2 = xw[((long)(p2 & 0xFFFF) << 12) + ((p2 >> 16) << 8) + h];
      float v3 = xw[((long)(p3 & 0xFFFF) << 12) + ((p3 >> 16) << 8) + h];
      a0 += v0 * inv[p0 >> 16];
      a1 += v1 * inv[p1 >> 16];
      a2 += v2 * inv[p2 >> 16];
      a3 += v3 * inv[p3 >> 16];
    }
    for (; i < n; ++i) {
      int pk = se[i];
      a0 += xw[((long)(pk & 0xFFFF) << 12) + ((pk >> 16) << 8) + h] * inv[pk >> 16];
    }
  }
  float tot = out1[((long)dst << 8) + h] + ((a0 + a1) + (a2 + a3));
  out1[((long)dst << 8) + h] = tot;
  __hip_bfloat16 hv = __float2bfloat16(tot);
  long d = (long)dst * 512 + 256 + h;
  a2o1_hi[d] = hv;
  a2o1_lo[d] = __float2bfloat16(tot - __bfloat162float(hv));
}

// a2o1 cols 0:256 = sum_{src->dst} out1[src] (split)
__global__ __launch_bounds__(256) void graphconv_gather(
    const int* __restrict__ rowptr, const int* __restrict__ eidx,
    const float* __restrict__ out1, __hip_bfloat16* __restrict__ a2o1_hi,
    __hip_bfloat16* __restrict__ a2o1_lo) {
  const int dst = blockIdx.x;
  const int h = threadIdx.x;
  __shared__ int se[256];
  const int beg = rowptr[dst], end = rowptr[dst + 1];
  float a0 = 0.f, a1 = 0.f, a2 = 0.f, a3 = 0.f;
  for (int c0 = beg; c0 < end; c0 += 256) {
    int n = min(256, end - c0);
    __syncthreads();
    if (h < n) se[h] = eidx[c0 + h];
    __syncthreads();
    int i = 0;
    for (; i + 4 <= n; i += 4) {
      a0 += out1[((long)(se[i] & 0xFFFF) << 8) + h];
      a1 += out1[((long)(se[i + 1] & 0xFFFF) << 8) + h];
      a2 += out1[((long)(se[i + 2] & 0xFFFF) << 8) + h];
      a3 += out1[((long)(se[i + 3] & 0xFFFF) << 8) + h];
    }
    for (; i < n; ++i) a0 += out1[((long)(se[i] & 0xFFFF) << 8) + h];
  }
  float acc = (a0 + a1) + (a2 + a3);
  __hip_bfloat16 hv = __float2bfloat16(acc);
  long d = (long)dst * 512 + h;
  a2o1_hi[d] = hv;
  a2o1_lo[d] = __float2bfloat16(acc - __bfloat162float(hv));
}

// ---------------- logits + log_softmax over batch axis (faithful dim=1) -------
__global__ __launch_bounds__(256) void logits_lsm(
    const float* __restrict__ hidden, const float* __restrict__ w_fc,
    const float* __restrict__ b_fc, void* __restrict__ out_v,
    const int* __restrict__ flag) {
  __shared__ float wf[256 * 7];
  __shared__ float lg[224];
  __shared__ float corr[7];
  int t = blockIdx.x;
  int tid = threadIdx.x;
  for (int i = tid; i < 256 * 7; i += 256) wf[i] = w_fc[i];
  __syncthreads();
  if (tid < 224) {
    int b = tid / 7, c = tid % 7;
    const float* hr = hidden + ((long)((b << 8) + t) << 8);
    float s = b_fc[c];
    for (int k = 0; k < 256; ++k) s += hr[k] * wf[k * 7 + c];
    lg[tid] = s;
  }
  __syncthreads();
  if (tid < 7) {
    float m = -1e30f;
    for (int b = 0; b < BB; ++b) m = fmaxf(m, lg[b * 7 + tid]);
    float sum = 0.f;
    for (int b = 0; b < BB; ++b) sum += __expf(lg[b * 7 + tid] - m);
    corr[tid] = m + logf(sum);
  }
  __syncthreads();
  if (tid < 224) {
    float v = lg[tid] - corr[tid % 7];
    if (flag[0]) ((float*)out_v)[t * 224 + tid] = v;
    else ((__hip_bfloat16*)out_v)[t * 224 + tid] = __float2bfloat16(v);
  }
}

extern "C" void kernel_launch(void* const* d_in, const int* in_sizes, int n_in,
                              void* d_out, int out_size, void* d_ws, size_t ws_size,
                              hipStream_t stream) {
  const int* ei = (const int*)d_in[1];
  const int* et = (const int*)d_in[3];

  float* ws = (float*)d_ws;
  int* flag = (int*)d_ws;
  float* p = ws + 16;
  auto alloc = [&](long nf) { float* r = p; p += nf; return r; };
  float* w_fc_f = alloc(1792);
  float* b_rel_f = alloc(256);
  float* biasx = alloc(4352);                                    // [0..4095]=0, tail=bias1
  float* battx = alloc(1024);                                    // [0..767]=b_att, rest 0
  float* b_lin_f = alloc(256);
  float* b_fc_f = alloc(16);
  __hip_bfloat16* x_hi = (__hip_bfloat16*)alloc(2097152);        // [8192][512]
  __hip_bfloat16* x_lo = (__hip_bfloat16*)alloc(2097152);
  __hip_bfloat16* wae_hi = (__hip_bfloat16*)alloc(393216);       // [1024][768] = [w_att|w_lin]^T
  __hip_bfloat16* wae_lo = (__hip_bfloat16*)alloc(393216);
  __hip_bfloat16* wrr_hi = (__hip_bfloat16*)alloc(65536);        // [256][512] = [w_rel;w_root]^T
  __hip_bfloat16* wrr_lo = (__hip_bfloat16*)alloc(65536);
  __hip_bfloat16* wtc_hi = (__hip_bfloat16*)alloc(1114112);      // [4352][512]
  __hip_bfloat16* wtc_lo = (__hip_bfloat16*)alloc(1114112);
  float* basis_f = alloc(3932160);
  float* comp_f = alloc(512);
  float* xw = alloc(33554432);   // fp32 [8192][4096]; overlays below
  float* cnt = alloc(131072);
  float* out1 = alloc(2097152);
  __hip_bfloat16* a2o1_hi = (__hip_bfloat16*)alloc(2097152);     // [8192][512]
  __hip_bfloat16* a2o1_lo = (__hip_bfloat16*)alloc(2097152);
  float* hidden = alloc(2097152);
  int* rowptr = (int*)alloc(8208);
  int* fillc = (int*)alloc(8192);
  int* eidx = (int*)alloc(262144);
  // wt_nat overlays head of xw (consumed by wt_transpose before xw is written)
  float* wt_nat = xw;                                            // [16][512][256]
  // phase B overlays the (consumed) xw region
  float* em = xw;
  __hip_bfloat16* emwT_hi = (__hip_bfloat16*)(em + 2097152);     // [32][256][256]
  __hip_bfloat16* emwT_lo = (__hip_bfloat16*)(em + 3145728);
  __hip_bfloat16* em_hi = (__hip_bfloat16*)(em + 6291456);       // [8192][768]
  __hip_bfloat16* em_lo = (__hip_bfloat16*)(em + 9437184);
  __hip_bfloat16* X_hi = (__hip_bfloat16*)(em + 12582912);
  __hip_bfloat16* X_lo = (__hip_bfloat16*)(em + 15728640);
  __hip_bfloat16* a_b16 = (__hip_bfloat16*)(em + 20971520);      // [32][256][256]

  // 0. dtype detect + one unified prep launch (also zeroes cnt)
  detect_dtype<<<1, 256, 0, stream>>>((const unsigned short*)d_in[0], flag);
  PTable T{};
  long tot = 0;
  int ns = 0;
  auto segL = [&](const void* s, float* d, __hip_bfloat16* hi, __hip_bfloat16* lo,
                  long n, int z) {
    T.seg[ns] = PSeg{s, d, hi, lo, n, 0, 0, 0, 0, 0, z};
    ns++; tot += n;
  };
  auto segT = [&](const void* s, __hip_bfloat16* hi, __hip_bfloat16* lo,
                  int R, int C, int ld, int off) {
    T.seg[ns] = PSeg{s, nullptr, hi, lo, (long)R * C, R, C, ld, off, 1, 0};
    ns++; tot += (long)R * C;
  };
  segL(d_in[0], nullptr, x_hi, x_lo, NN * FF, 0);
  segL(d_in[8], basis_f, nullptr, nullptr, NBASE * FF * HH, 0);
  segL(d_in[9], comp_f, nullptr, nullptr, RR * NBASE, 0);
  segL(d_in[13], b_rel_f, nullptr, nullptr, HH, 0);
  segL(d_in[16], battx, nullptr, nullptr, DD, 0);
  segL(nullptr, battx + DD, nullptr, nullptr, 256, 1);
  segL(d_in[18], b_lin_f, nullptr, nullptr, HH, 0);
  segL(d_in[19], w_fc_f, nullptr, nullptr, HH * CC, 0);
  segL(d_in[20], b_fc_f, nullptr, nullptr, CC, 0);
  segL(nullptr, biasx, nullptr, nullptr, 4096, 1);
  segL(d_in[11], biasx + 4096, nullptr, nullptr, HH, 0);
  segL(nullptr, cnt, nullptr, nullptr, 131072, 1);               // zero cnt
  segT(d_in[15], wae_hi, wae_lo, DD, DD, DD, 0);                 // w_att^T -> rows 0:768
  segT(d_in[17], wae_hi + 768 * 768, wae_lo + 768 * 768, DD, HH, DD, 0);  // w_lin^T
  segT(d_in[10], wtc_hi + 4096 * 512, wtc_lo + 4096 * 512, FF, HH, FF, 0);  // root1^T
  segT(d_in[12], wrr_hi, wrr_lo, HH, HH, 512, 0);                // w_rel^T
  segT(d_in[14], wrr_hi, wrr_lo, HH, HH, 512, 256);              // w_root^T
  T.count = ns;
  T.total = tot;
  prep_all<<<4096, 256, 0, stream>>>(T, flag);

  // 1. Wt: coalesced GEMM into natural layout, then LDS-tiled transpose + split
  wt_gemm<<<131072 / 256, 256, 0, stream>>>(basis_f, comp_f, wt_nat);
  wt_transpose<<<dim3(8, 16, 16), 256, 0, stream>>>(wt_nat, wtc_hi, wtc_lo);
  // 2. merged xw|out1 = x @ [W | root1] + [0 | bias1]  (cols>=4096 -> out1)
  mfma_dual<<<dim3(34, 64, 1), 256, 0, stream>>>(
      x_hi, x_lo, wtc_hi, wtc_lo, biasx, xw, out1, nullptr, nullptr, nullptr, nullptr,
      FF, 4096, 0, 0, 0, FLAG_BIAS | FLAG_TAILOUT);
  // 3. CSR build (cnt zeroed by prep_all)
  count_edges<<<EE / 256, 256, 0, stream>>>(ei, et, cnt);
  scan_rowptr<<<1, 256, 0, stream>>>(cnt, rowptr, fillc);
  edge_fill<<<EE / 256, 256, 0, stream>>>(ei, et, rowptr, fillc, eidx);
  // 4/5. aggregations (gather); emit [agg2|out1] hi/lo as out2-GEMM A operand
  rgcn_gather<<<NN, 256, 0, stream>>>(rowptr, eidx, cnt, xw, out1, a2o1_hi, a2o1_lo);
  graphconv_gather<<<NN, 256, 0, stream>>>(rowptr, eidx, out1, a2o1_hi, a2o1_lo);
  // 6. em cols 0:512 = x (split, after xw is dead); cols 512:768 = out2
  copy_xsplit_k<<<(NN * FF) / 256, 256, 0, stream>>>(x_hi, x_lo, em_hi, em_lo);
  mfma_dual<<<dim3(2, 64, 1), 256, 0, stream>>>(
      a2o1_hi, a2o1_lo, wrr_hi, wrr_lo, b_rel_f, nullptr, nullptr,
      em_hi + 512, em_lo + 512, nullptr, nullptr, 512, DD, 0, 0, 0,
      FLAG_BIAS | FLAG_SPLITOUT);
  // 7. [X | emwT] = em @ [w_att | w_lin] (+b_att|0); cols>=768 -> transposed split
  mfma_dual<<<dim3(8, 64, 1), 256, 0, stream>>>(
      em_hi, em_lo, wae_hi, wae_lo, battx, nullptr, nullptr, X_hi, X_lo,
      emwT_hi, emwT_lo, DD, DD, 0, 0, 0, FLAG_BIAS | FLAG_SPLITOUT | FLAG_TAIL2);
  // 8. a = softmax(tanh(X_b . em_b^T)) fused, bf16 out
  score_softmax<<<dim3(1, 2, BB), 256, 0, stream>>>(X_hi, X_lo, em_hi, em_lo, a_b16);
  // 9. hidden = relu(a @ emwT + b_lin)
  mfma_dual<<<dim3(2, 2, BB), 256, 0, stream>>>(
      a_b16, nullptr, emwT_hi, emwT_lo, b_lin_f, hidden, nullptr, nullptr, nullptr,
      nullptr, nullptr, LL, HH, (long)LL * LL, (long)LL * HH, (long)LL * HH,
      FLAG_BIAS | FLAG_RELU);
  // 10. logits + log_softmax over batch axis
  logits_lsm<<<LL, 256, 0, stream>>>(hidden, w_fc_f, b_fc_f, d_out, flag);
}